// Round 10
// baseline (136.496 us; speedup 1.0000x reference)
//
#include <hip/hip_runtime.h>
#include <math.h>

#define NN 8
#define CC 20
#define PP 8732
#define MM 16
#define NPR 3
#define SPLIT 3
#define CH 2911              // ceil(PP/SPLIT)
#define ROWS (NN * CC)

__device__ __forceinline__ float fast_rcp(float x) { return __builtin_amdgcn_rcpf(x); }
__device__ __forceinline__ float rfl(float x) {   // force wave-uniform value into SGPR
    return __uint_as_float(__builtin_amdgcn_readfirstlane(__float_as_uint(x)));
}

// fast lse over 2 logits: mx + log(1 + exp(-|a-b|)); identical code in both
// kernels so recomputed terms cancel bit-exactly.
__device__ __forceinline__ float lse2(float a, float b) {
    float mx = fmaxf(a, b);
    float d  = fabsf(a - b);
    return mx + __logf(1.0f + __expf(-d));
}

// ---------------- Kernel A: IoU matching + pos stats (1024-thread blocks, SGPR boxes) ----------------
#define ABLK 1024
#define ANW 16
__global__ __launch_bounds__(ABLK) void mbox_p1(
    const float* __restrict__ locs, const float* __restrict__ scores,
    const float* __restrict__ boxes, const int* __restrict__ labels,
    const float* __restrict__ priors,
    unsigned char* __restrict__ pk8,
    unsigned long long* __restrict__ partials, float* __restrict__ cstats,
    unsigned int* __restrict__ counters)
{
    const int row = blockIdx.x / SPLIT;
    const int chunk = blockIdx.x - row * SPLIT;
    const int tid = threadIdx.x, lane = tid & 63, wav = tid >> 6;

    if (blockIdx.x == 0 && tid == 0) counters[0] = 0u;

    __shared__ float s_bcx[MM], s_bcy[MM], s_bw[MM], s_bh[MM];
    __shared__ unsigned int s_pk[ANW * MM];
    __shared__ float s_rf[ANW * 3];

    // wave-uniform box data -> readfirstlane -> SGPR residency
    float bx1[MM], by1[MM], bx2[MM], by2[MM], bar[MM];
    unsigned int labm = 0;
    {
        const float* bb = boxes + (size_t)row * MM * 4;
        const int*   lb = labels + (size_t)row * MM;
#pragma unroll
        for (int m = 0; m < MM; m++) {
            float x1 = rfl(bb[m * 4 + 0]), y1 = rfl(bb[m * 4 + 1]);
            float x2 = rfl(bb[m * 4 + 2]), y2 = rfl(bb[m * 4 + 3]);
            bx1[m] = x1; by1[m] = y1; bx2[m] = x2; by2[m] = y2;
            bar[m] = rfl((x2 - x1) * (y2 - y1));
            labm |= (lb[m] != 0 ? 1u : 0u) << m;
        }
        labm = __builtin_amdgcn_readfirstlane(labm);
    }
    if (tid < MM) {
        s_bcx[tid] = (bx1[tid] + bx2[tid]) * 0.5f;
        s_bcy[tid] = (by1[tid] + by2[tid]) * 0.5f;
        s_bw[tid]  = bx2[tid] - bx1[tid];
        s_bh[tid]  = by2[tid] - by1[tid];
    }
    __syncthreads();

    const float4* pri4 = (const float4*)priors;
    const float4* loc4 = (const float4*)(locs + (size_t)row * PP * 4);
    const float2* sc2  = (const float2*)(scores + (size_t)row * PP * 2);
    unsigned char* pk  = pk8 + (size_t)row * PP;

    // bestk[m]: (iou_bits & ~0xFFF) | ((2-k)<<10) | (1023-tid)
    //   u32-max == (max trunc-iou, then min k, then min tid) == (max iou, min p)
    unsigned int bestk[MM];
#pragma unroll
    for (int m = 0; m < MM; m++) bestk[m] = 0u;
    float l_np = 0.0f, l_l1 = 0.0f, l_cp = 0.0f;
    const int p0 = chunk * CH, p1e = min(p0 + CH, PP);

    // prefetch all 3 priors up-front (clamped; masked lanes never use the value)
    float4 prv[3];
#pragma unroll
    for (int k = 0; k < 3; k++) {
        int p = p0 + tid + k * ABLK;
        prv[k] = pri4[min(p, PP - 1)];
    }

#pragma unroll
    for (int k = 0; k < 3; k++) {
        const int p = p0 + tid + k * ABLK;
        if (p < p1e) {
            const float4 pr = prv[k];
            const unsigned int lowb = ((unsigned int)(2 - k) << 10) | (unsigned int)(1023 - tid);
            float hw = pr.z * 0.5f, hh = pr.w * 0.5f;
            float px1 = pr.x - hw, py1 = pr.y - hh;
            float px2 = pr.x + hw, py2 = pr.y + hh;
            float area_b = (px2 - px1) * (py2 - py1);
            unsigned int bovk = 0u;
#pragma unroll
            for (int m = 0; m < MM; m++) {
                float dx = fminf(bx2[m], px2) - fmaxf(bx1[m], px1);
                float dy = fminf(by2[m], py2) - fmaxf(by1[m], py1);
                dx = fmaxf(dx, 0.0f); dy = fmaxf(dy, 0.0f);
                float inter = dx * dy;
                float den = (bar[m] + area_b) - inter;
                float iou = inter * fast_rcp(den);
                unsigned int ib = __float_as_uint(iou);
                unsigned int km = (ib & 0xFFFFFFF0u) | (unsigned int)(15 - m);   // v_and_or
                bovk = max(bovk, km);                                            // v_max_u32
                unsigned int kp = (ib & 0xFFFFF000u) | lowb;                     // v_and_or
                bestk[m] = max(bestk[m], kp);                                    // v_max_u32
            }
            int bm = 15 - (int)(bovk & 15u);
            bool pos = (bovk >= 0x3F000000u) && (((labm >> bm) & 1u) != 0u);
            pk[p] = (unsigned char)((pos ? 16u : 0u) | (unsigned)bm);
            if (pos) {   // rare, divergent cold path
                float2 sc = sc2[p];
                float4 pl = loc4[p];
                l_np += 1.0f;
                l_cp += lse2(sc.x, sc.y) - sc.y;
                float tx = (s_bcx[bm] - pr.x) * 10.0f / pr.z;
                float ty = (s_bcy[bm] - pr.y) * 10.0f / pr.w;
                float tw = __logf(s_bw[bm] / pr.z) * 5.0f;
                float th = __logf(s_bh[bm] / pr.w) * 5.0f;
                l_l1 += fabsf(pl.x - tx) + fabsf(pl.y - ty) + fabsf(pl.z - tw) + fabsf(pl.w - th);
            }
        }
    }

    // per-object argmax reduce: u32 keys (ties impossible — tid bits differ)
#pragma unroll
    for (int m = 0; m < MM; m++) {
        unsigned int key = bestk[m];
#pragma unroll
        for (int off = 32; off; off >>= 1) {
            unsigned int o = __shfl_down(key, off);
            if (o > key) key = o;
        }
        if (lane == 0) s_pk[wav * MM + m] = key;
    }
#pragma unroll
    for (int off = 32; off; off >>= 1) {
        l_np += __shfl_down(l_np, off);
        l_l1 += __shfl_down(l_l1, off);
        l_cp += __shfl_down(l_cp, off);
    }
    if (lane == 0) { s_rf[wav * 3] = l_np; s_rf[wav * 3 + 1] = l_l1; s_rf[wav * 3 + 2] = l_cp; }
    __syncthreads();
    if (tid < MM) {
        unsigned int key = s_pk[tid];
        for (int w = 1; w < ANW; w++) {
            unsigned int o = s_pk[w * MM + tid];
            if (o > key) key = o;
        }
        int tw  = 1023 - (int)(key & 1023u);
        int itw = 2 - (int)((key >> 10) & 3u);
        int pm  = p0 + itw * ABLK + tw;
        // global partial: (trunc-iou, 0x7fffffff - p); trunc is chunk-consistent
        partials[((size_t)row * MM + tid) * SPLIT + chunk] =
            ((unsigned long long)(key & 0xFFFFF000u) << 32) |
            (unsigned int)(0x7fffffff - pm);
    }
    if (tid == 0) {
        float np = 0, l1 = 0, cp = 0;
        for (int w = 0; w < ANW; w++) { np += s_rf[w * 3]; l1 += s_rf[w * 3 + 1]; cp += s_rf[w * 3 + 2]; }
        float* cs = cstats + ((size_t)row * SPLIT + chunk) * 3;
        cs[0] = np; cs[1] = l1; cs[2] = cp;
    }
}

// ---------------- Kernel B: force prologue + ce + histogram radix-select + finisher finalize ----------------
#define CBLK 1024
#define EPT 9   // ceil(PP / CBLK)
__global__ __launch_bounds__(CBLK) void mbox_sel(
    const float* __restrict__ locs, const float* __restrict__ scores,
    const float* __restrict__ boxes, const int* __restrict__ labels,
    const float* __restrict__ priors,
    const unsigned char* __restrict__ pk8,
    const unsigned long long* __restrict__ partials,
    const float* __restrict__ cstats, float* __restrict__ rstats,
    unsigned int* __restrict__ counters, float* __restrict__ out)
{
    const int row = blockIdx.x, tid = threadIdx.x, lane = tid & 63, wav = tid >> 6;
    __shared__ float s_bcx[MM], s_bcy[MM], s_bw[MM], s_bh[MM];
    __shared__ int s_lab[MM], s_pfo[MM], s_fp[MM];
    __shared__ float s_fv[MM], s_sum[3];
    __shared__ unsigned int s_hist[256];
    __shared__ unsigned int s_prefix, s_Kr, s_K, s_fin;
    __shared__ float s_redf[16];
    __shared__ int s_redi[16];

    if (tid < MM) {
        s_fp[tid] = -1;
        const float* b = boxes + ((size_t)row * MM + tid) * 4;
        float x1 = b[0], y1 = b[1], x2 = b[2], y2 = b[3];
        s_bcx[tid] = (x1 + x2) * 0.5f; s_bcy[tid] = (y1 + y2) * 0.5f;
        s_bw[tid] = x2 - x1; s_bh[tid] = y2 - y1;
        s_lab[tid] = labels[row * MM + tid];
        const unsigned long long* pr = partials + ((size_t)row * MM + tid) * SPLIT;
        unsigned long long key = pr[0];
        for (int c = 1; c < SPLIT; c++) { unsigned long long o = pr[c]; if (o > key) key = o; }
        s_pfo[tid] = 0x7fffffff - (int)(unsigned)(key & 0xffffffffull);
    }
    if (tid >= 16 && tid < 19) {
        int j = tid - 16; float s = 0;
        for (int c = 0; c < SPLIT; c++) s += cstats[((size_t)row * SPLIT + c) * 3 + j];
        s_sum[j] = s;
    }
    __syncthreads();

    // force deltas (sequential last-wins == group by prior, keep largest m)
    float d_np = 0, d_l1 = 0, d_cp = 0;
    if (tid < MM) {
        int p = s_pfo[tid];
        bool is_last = true;
        for (int mm = tid + 1; mm < MM; mm++) if (s_pfo[mm] == p) is_last = false;
        if (is_last) {
            const float4 pr = ((const float4*)priors)[p];
            const float4 pl = ((const float4*)(locs + (size_t)row * PP * 4))[p];
            const float2 sc = ((const float2*)(scores + (size_t)row * PP * 2))[p];
            float lse = lse2(sc.x, sc.y);
            unsigned int u = pk8[(size_t)row * PP + p];
            if (u & 16u) {   // remove old positive contribution
                int mo = u & 15;
                d_np -= 1.0f; d_cp -= (lse - sc.y);
                float tx = (s_bcx[mo] - pr.x) * 10.0f / pr.z;
                float ty = (s_bcy[mo] - pr.y) * 10.0f / pr.w;
                float tw = __logf(s_bw[mo] / pr.z) * 5.0f;
                float th = __logf(s_bh[mo] / pr.w) * 5.0f;
                d_l1 -= fabsf(pl.x - tx) + fabsf(pl.y - ty) + fabsf(pl.z - tw) + fabsf(pl.w - th);
            }
            if (s_lab[tid] != 0) {   // add forced positive (ov=1, m=tid)
                d_np += 1.0f; d_cp += (lse - sc.y);
                float tx = (s_bcx[tid] - pr.x) * 10.0f / pr.z;
                float ty = (s_bcy[tid] - pr.y) * 10.0f / pr.w;
                float tw = __logf(s_bw[tid] / pr.z) * 5.0f;
                float th = __logf(s_bh[tid] / pr.w) * 5.0f;
                d_l1 += fabsf(pl.x - tx) + fabsf(pl.y - ty) + fabsf(pl.z - tw) + fabsf(pl.w - th);
                s_fv[tid] = 0.0f;                          // forced positive -> ce 0
            } else {
                s_fv[tid] = fmaxf(lse - sc.x, 0.0f);       // forced but label 0 -> negative ce
            }
            s_fp[tid] = p;
        }
    }
    if (tid < 64) {
#pragma unroll
        for (int off = 32; off; off >>= 1) {
            d_np += __shfl_down(d_np, off);
            d_l1 += __shfl_down(d_l1, off);
            d_cp += __shfl_down(d_cp, off);
        }
        if (tid == 0) {
            float np = s_sum[0] + d_np;
            rstats[(size_t)row * 8 + 0] = np;
            rstats[(size_t)row * 8 + 1] = s_sum[1] + d_l1;
            rstats[(size_t)row * 8 + 2] = s_sum[2] + d_cp;
            int K = NPR * (int)(np + 0.5f);
            s_K = (K > 0) ? (unsigned)K : 0u;
            s_prefix = 0u;
            s_Kr = (K > 0) ? (unsigned)K : 0u;
        }
    }
    __syncthreads();

    // compute ce_neg bit-patterns into registers, apply forced-prior fixes
    const float2* sc2 = (const float2*)(scores + (size_t)row * PP * 2);
    const unsigned char* pk = pk8 + (size_t)row * PP;
    unsigned int uv[EPT];
#pragma unroll
    for (int k = 0; k < EPT; k++) {
        int p = tid + k * CBLK;
        if (p < PP) {
            unsigned int u8 = pk[p];
            float2 sc = sc2[p];
            float ce = (u8 & 16u) ? 0.0f : fmaxf(lse2(sc.x, sc.y) - sc.x, 0.0f);
            uv[k] = __float_as_uint(ce);
        } else uv[k] = 0u;
    }
    for (int t = 0; t < MM; t++) {
        int fp = s_fp[t];
        if (fp >= 0) {
            unsigned int fb = __float_as_uint(s_fv[t]);
#pragma unroll
            for (int k = 0; k < EPT; k++) if (tid + k * CBLK == fp) uv[k] = fb;
        }
    }

    // 4-pass 256-bin histogram radix select for the K-th largest bit pattern
    const unsigned int K = s_K;
    unsigned int T = 0u;
    if (K > 0u && K < PP) {
        for (int pass = 0; pass < 4; pass++) {
            const int shift = 24 - 8 * pass;
            if (tid < 256) s_hist[tid] = 0u;
            __syncthreads();
            const unsigned int pref   = s_prefix;
            const unsigned int maskhi = (pass == 0) ? 0u : (0xffffffffu << (shift + 8));
#pragma unroll
            for (int k = 0; k < EPT; k++) {
                unsigned int u = uv[k];
                if ((u & maskhi) == pref) atomicAdd(&s_hist[(u >> shift) & 255u], 1u);
            }
            __syncthreads();
            if (wav == 0) {
                unsigned int Kr = s_Kr;
                unsigned int h0 = s_hist[lane * 4 + 0];
                unsigned int h1 = s_hist[lane * 4 + 1];
                unsigned int h2 = s_hist[lane * 4 + 2];
                unsigned int h3 = s_hist[lane * 4 + 3];
                unsigned int c3 = h3;
                unsigned int c2 = h3 + h2;
                unsigned int c1 = c2 + h1;
                unsigned int c0 = c1 + h0;
                unsigned int suf = c0;
#pragma unroll
                for (int off = 1; off < 64; off <<= 1) {
                    unsigned int o = __shfl_down(suf, off);
                    if (lane + off < 64) suf += o;
                }
                unsigned int above = suf - c0;
                int cand = -1;
                unsigned int G = 0;
                if      (c3 + above >= Kr) { cand = lane * 4 + 3; G = above + c3 - h3; }
                else if (c2 + above >= Kr) { cand = lane * 4 + 2; G = above + c2 - h2; }
                else if (c1 + above >= Kr) { cand = lane * 4 + 1; G = above + c1 - h1; }
                else if (c0 + above >= Kr) { cand = lane * 4 + 0; G = above + c0 - h0; }
                int best = cand;
#pragma unroll
                for (int off = 32; off; off >>= 1) best = max(best, __shfl_down(best, off));
                best = __shfl(best, 0);
                if (cand == best && cand >= 0) {
                    s_Kr = Kr - G;
                    s_prefix = pref | ((unsigned int)best << shift);
                }
            }
            __syncthreads();
        }
        T = s_prefix;
    }

    // sum strictly greater than pivot + ties * pivot
    float sgt = 0.0f; int cgt = 0;
    if (K > 0u) {
#pragma unroll
        for (int k = 0; k < EPT; k++) {
            unsigned int u = uv[k];
            if (u > T) { sgt += __uint_as_float(u); cgt++; }
        }
    }
#pragma unroll
    for (int off = 32; off; off >>= 1) {
        sgt += __shfl_down(sgt, off);
        cgt += __shfl_down(cgt, off);
    }
    if (lane == 0) { s_redf[wav] = sgt; s_redi[wav] = cgt; }
    __syncthreads();
    if (tid == 0) {
        float s = 0; int cnt = 0;
        for (int w = 0; w < 16; w++) { s += s_redf[w]; cnt += s_redi[w]; }
        float chard = (K > 0u) ? (s + (float)(int)(K - (unsigned)cnt) * __uint_as_float(T)) : 0.0f;
        rstats[(size_t)row * 8 + 4] = chard;
        // ---- elect the global finisher (last of 160 rows), device-scope release/acquire ----
        __threadfence();
        unsigned int old = __hip_atomic_fetch_add(&counters[0], 1u,
                                                  __ATOMIC_ACQ_REL, __HIP_MEMORY_SCOPE_AGENT);
        s_fin = (old == ROWS - 1) ? 1u : 0u;
        if (s_fin) __threadfence();
    }
    __syncthreads();
    if (!s_fin) return;

    // finalize (one block total; cold path, wave 0 only)
    if (tid < 64) {
        int c = tid;
        float loss = 0.0f;
        if (c < CC) {
            float np = 0, l1 = 0, cp = 0, ch = 0;
            for (int n = 0; n < NN; n++) {
                const float* s = rstats + ((size_t)(n * CC + c)) * 8;
                np += s[0]; l1 += s[1]; cp += s[2]; ch += s[4];
            }
            float loc = l1 / fmaxf(np * 4.0f, 1.0f);
            float val = (np > 0.0f) ? (cp + ch + loc) / fmaxf(np, 1.0f) : 0.0f;
            loss = val / (float)CC;
        }
#pragma unroll
        for (int off = 32; off; off >>= 1) loss += __shfl_down(loss, off);
        if (tid == 0) out[0] = loss;
    }
}

extern "C" void kernel_launch(void* const* d_in, const int* in_sizes, int n_in,
                              void* d_out, int out_size, void* d_ws, size_t ws_size,
                              hipStream_t stream) {
    const float* locs   = (const float*)d_in[0];
    const float* scores = (const float*)d_in[1];
    const float* boxes  = (const float*)d_in[2];
    const int*   labels = (const int*)d_in[3];
    const float* priors = (const float*)d_in[4];
    float* out = (float*)d_out;

    char* ws = (char*)d_ws;
    unsigned char* pk8           = (unsigned char*)ws;                  // 1,397,120 B
    unsigned long long* partials = (unsigned long long*)(ws + 1397120); //    61,440 B (160*16*3*8)
    float* cstats                = (float*)(ws + 1458560);              //     5,760 B (160*3*3*4)
    float* rstats                = (float*)(ws + 1464320);              //     5,120 B
    unsigned int* counters       = (unsigned int*)(ws + 1469440);       //         4 B

    mbox_p1<<<ROWS * SPLIT, ABLK, 0, stream>>>(locs, scores, boxes, labels, priors,
                                               pk8, partials, cstats, counters);
    mbox_sel<<<ROWS, CBLK, 0, stream>>>(locs, scores, boxes, labels, priors,
                                        pk8, partials, cstats, rstats, counters, out);
}

// Round 11
// 124.866 us; speedup vs baseline: 1.0931x; 1.0931x over previous
//
#include <hip/hip_runtime.h>
#include <math.h>

#define NN 8
#define CC 20
#define PP 8732
#define MM 16
#define NPR 3
#define SPLIT 12
#define CH 728               // ceil(PP/SPLIT)
#define ROWS (NN * CC)

__device__ __forceinline__ float fast_rcp(float x) { return __builtin_amdgcn_rcpf(x); }
__device__ __forceinline__ float rfl(float x) {   // force wave-uniform value into SGPR
    return __uint_as_float(__builtin_amdgcn_readfirstlane(__float_as_uint(x)));
}

// fast lse over 2 logits: mx + log(1 + exp(-|a-b|)); identical code in both
// kernels so recomputed terms cancel bit-exactly.
__device__ __forceinline__ float lse2(float a, float b) {
    float mx = fmaxf(a, b);
    float d  = fabsf(a - b);
    return mx + __logf(1.0f + __expf(-d));
}

// ---------------- Kernel A: IoU matching + pos stats (SGPR boxes, packed-u32 argmax) ----------------
#define ABLK 256
__global__ __launch_bounds__(ABLK) void mbox_p1(
    const float* __restrict__ locs, const float* __restrict__ scores,
    const float* __restrict__ boxes, const int* __restrict__ labels,
    const float* __restrict__ priors,
    unsigned char* __restrict__ pk8,
    unsigned long long* __restrict__ partials, float* __restrict__ cstats)
{
    const int row = blockIdx.x / SPLIT;
    const int chunk = blockIdx.x - row * SPLIT;
    const int tid = threadIdx.x, lane = tid & 63, wav = tid >> 6;

    // cold-path data (divergent bm index) lives in LDS; hot loop never touches LDS
    __shared__ float s_bcx[MM], s_bcy[MM], s_bw[MM], s_bh[MM];
    __shared__ unsigned int s_pk[4 * MM];
    __shared__ float s_rf[4 * 3];

    // wave-uniform box data -> readfirstlane -> SGPR residency (not VGPR, not scratch)
    float bx1[MM], by1[MM], bx2[MM], by2[MM], bar[MM];
    unsigned int labm = 0;
    {
        const float* bb = boxes + (size_t)row * MM * 4;
        const int*   lb = labels + (size_t)row * MM;
#pragma unroll
        for (int m = 0; m < MM; m++) {
            float x1 = rfl(bb[m * 4 + 0]), y1 = rfl(bb[m * 4 + 1]);
            float x2 = rfl(bb[m * 4 + 2]), y2 = rfl(bb[m * 4 + 3]);
            bx1[m] = x1; by1[m] = y1; bx2[m] = x2; by2[m] = y2;
            bar[m] = rfl((x2 - x1) * (y2 - y1));
            labm |= (lb[m] != 0 ? 1u : 0u) << m;
        }
        labm = __builtin_amdgcn_readfirstlane(labm);
    }
    if (tid < MM) {
        s_bcx[tid] = (bx1[tid] + bx2[tid]) * 0.5f;
        s_bcy[tid] = (by1[tid] + by2[tid]) * 0.5f;
        s_bw[tid]  = bx2[tid] - bx1[tid];
        s_bh[tid]  = by2[tid] - by1[tid];
    }
    __syncthreads();

    const float4* pri4 = (const float4*)priors;
    const float4* loc4 = (const float4*)(locs + (size_t)row * PP * 4);
    const float2* sc2  = (const float2*)(scores + (size_t)row * PP * 2);
    unsigned char* pk  = pk8 + (size_t)row * PP;

    // bestk[m]: (iou_bits & ~0x7FF) | ((7-it)<<8) | (255-tid)
    //   u32-max == (max trunc-iou, then min it, then min tid) == (max iou, min p)
    unsigned int bestk[MM];
#pragma unroll
    for (int m = 0; m < MM; m++) bestk[m] = 0u;
    float l_np = 0.0f, l_l1 = 0.0f, l_cp = 0.0f;
    const int p0 = chunk * CH, p1e = min(p0 + CH, PP);

    float4 pr_next;
    if (p0 + tid < p1e) pr_next = pri4[p0 + tid];
    int it = 0;
    for (int p = p0 + tid; p < p1e; p += ABLK, ++it) {
        float4 pr = pr_next;
        if (p + ABLK < p1e) pr_next = pri4[p + ABLK];   // prefetch next iteration
        const unsigned int lowb = ((unsigned int)(7 - it) << 8) | (unsigned int)(255 - tid);
        float hw = pr.z * 0.5f, hh = pr.w * 0.5f;
        float px1 = pr.x - hw, py1 = pr.y - hh;
        float px2 = pr.x + hw, py2 = pr.y + hh;
        float area_b = (px2 - px1) * (py2 - py1);
        // bovk: (iou_bits & ~15) | (15-m); u32-max == (max trunc-iou, min m)
        unsigned int bovk = 0u;
#pragma unroll
        for (int m = 0; m < MM; m++) {
            float dx = fminf(bx2[m], px2) - fmaxf(bx1[m], px1);
            float dy = fminf(by2[m], py2) - fmaxf(by1[m], py1);
            dx = fmaxf(dx, 0.0f); dy = fmaxf(dy, 0.0f);
            float inter = dx * dy;
            float den = (bar[m] + area_b) - inter;
            float iou = inter * fast_rcp(den);
            unsigned int ib = __float_as_uint(iou);
            unsigned int km = (ib & 0xFFFFFFF0u) | (unsigned int)(15 - m);   // v_and_or
            bovk = max(bovk, km);                                            // v_max_u32
            unsigned int kp = (ib & 0xFFFFF800u) | lowb;                     // v_and_or
            bestk[m] = max(bestk[m], kp);                                    // v_max_u32
        }
        int bm = 15 - (int)(bovk & 15u);
        bool pos = (bovk >= 0x3F000000u) && (((labm >> bm) & 1u) != 0u);
        pk[p] = (unsigned char)((pos ? 16u : 0u) | (unsigned)bm);
        if (pos) {   // rare, divergent cold path
            float2 sc = sc2[p];
            float4 pl = loc4[p];
            l_np += 1.0f;
            l_cp += lse2(sc.x, sc.y) - sc.y;
            float tx = (s_bcx[bm] - pr.x) * 10.0f / pr.z;
            float ty = (s_bcy[bm] - pr.y) * 10.0f / pr.w;
            float tw = __logf(s_bw[bm] / pr.z) * 5.0f;
            float th = __logf(s_bh[bm] / pr.w) * 5.0f;
            l_l1 += fabsf(pl.x - tx) + fabsf(pl.y - ty) + fabsf(pl.z - tw) + fabsf(pl.w - th);
        }
    }

    // per-object argmax reduce: u32 keys (ties impossible — tid bits differ)
#pragma unroll
    for (int m = 0; m < MM; m++) {
        unsigned int key = bestk[m];
#pragma unroll
        for (int off = 32; off; off >>= 1) {
            unsigned int o = __shfl_down(key, off);
            if (o > key) key = o;
        }
        if (lane == 0) s_pk[wav * MM + m] = key;
    }
#pragma unroll
    for (int off = 32; off; off >>= 1) {
        l_np += __shfl_down(l_np, off);
        l_l1 += __shfl_down(l_l1, off);
        l_cp += __shfl_down(l_cp, off);
    }
    if (lane == 0) { s_rf[wav * 3] = l_np; s_rf[wav * 3 + 1] = l_l1; s_rf[wav * 3 + 2] = l_cp; }
    __syncthreads();
    if (tid < MM) {
        unsigned int key = s_pk[tid];
        for (int w = 1; w < 4; w++) {
            unsigned int o = s_pk[w * MM + tid];
            if (o > key) key = o;
        }
        int tw  = 255 - (int)(key & 255u);
        int itw = 7 - (int)((key >> 8) & 7u);
        int pm  = p0 + itw * ABLK + tw;
        // global partial: (trunc-iou, 0x7fffffff - p); trunc is chunk-consistent
        partials[((size_t)row * MM + tid) * SPLIT + chunk] =
            ((unsigned long long)(key & 0xFFFFF800u) << 32) |
            (unsigned int)(0x7fffffff - pm);
    }
    if (tid == 0) {
        float np = 0, l1 = 0, cp = 0;
        for (int w = 0; w < 4; w++) { np += s_rf[w * 3]; l1 += s_rf[w * 3 + 1]; cp += s_rf[w * 3 + 2]; }
        float* cs = cstats + ((size_t)row * SPLIT + chunk) * 3;
        cs[0] = np; cs[1] = l1; cs[2] = cp;
    }
}

// ---------------- Kernel B: force prologue + ce + histogram radix-select top-K ----------------
#define CBLK 1024
#define EPT 9   // ceil(PP / CBLK)
__global__ __launch_bounds__(CBLK) void mbox_sel(
    const float* __restrict__ locs, const float* __restrict__ scores,
    const float* __restrict__ boxes, const int* __restrict__ labels,
    const float* __restrict__ priors,
    const unsigned char* __restrict__ pk8,
    const unsigned long long* __restrict__ partials,
    const float* __restrict__ cstats, float* __restrict__ rstats)
{
    const int row = blockIdx.x, tid = threadIdx.x, lane = tid & 63, wav = tid >> 6;
    __shared__ float s_bcx[MM], s_bcy[MM], s_bw[MM], s_bh[MM];
    __shared__ int s_lab[MM], s_pfo[MM], s_fp[MM];
    __shared__ float s_fv[MM], s_sum[3];
    __shared__ unsigned int s_hist[256];
    __shared__ unsigned int s_prefix, s_Kr, s_K;
    __shared__ float s_redf[16];
    __shared__ int s_redi[16];

    if (tid < MM) {
        s_fp[tid] = -1;
        const float* b = boxes + ((size_t)row * MM + tid) * 4;
        float x1 = b[0], y1 = b[1], x2 = b[2], y2 = b[3];
        s_bcx[tid] = (x1 + x2) * 0.5f; s_bcy[tid] = (y1 + y2) * 0.5f;
        s_bw[tid] = x2 - x1; s_bh[tid] = y2 - y1;
        s_lab[tid] = labels[row * MM + tid];
        const unsigned long long* pr = partials + ((size_t)row * MM + tid) * SPLIT;
        unsigned long long key = pr[0];
        for (int c = 1; c < SPLIT; c++) { unsigned long long o = pr[c]; if (o > key) key = o; }
        s_pfo[tid] = 0x7fffffff - (int)(unsigned)(key & 0xffffffffull);
    }
    if (tid >= 16 && tid < 19) {
        int j = tid - 16; float s = 0;
        for (int c = 0; c < SPLIT; c++) s += cstats[((size_t)row * SPLIT + c) * 3 + j];
        s_sum[j] = s;
    }
    __syncthreads();

    // force deltas (sequential last-wins == group by prior, keep largest m)
    float d_np = 0, d_l1 = 0, d_cp = 0;
    if (tid < MM) {
        int p = s_pfo[tid];
        bool is_last = true;
        for (int mm = tid + 1; mm < MM; mm++) if (s_pfo[mm] == p) is_last = false;
        if (is_last) {
            const float4 pr = ((const float4*)priors)[p];
            const float4 pl = ((const float4*)(locs + (size_t)row * PP * 4))[p];
            const float2 sc = ((const float2*)(scores + (size_t)row * PP * 2))[p];
            float lse = lse2(sc.x, sc.y);
            unsigned int u = pk8[(size_t)row * PP + p];
            if (u & 16u) {   // remove old positive contribution
                int mo = u & 15;
                d_np -= 1.0f; d_cp -= (lse - sc.y);
                float tx = (s_bcx[mo] - pr.x) * 10.0f / pr.z;
                float ty = (s_bcy[mo] - pr.y) * 10.0f / pr.w;
                float tw = __logf(s_bw[mo] / pr.z) * 5.0f;
                float th = __logf(s_bh[mo] / pr.w) * 5.0f;
                d_l1 -= fabsf(pl.x - tx) + fabsf(pl.y - ty) + fabsf(pl.z - tw) + fabsf(pl.w - th);
            }
            if (s_lab[tid] != 0) {   // add forced positive (ov=1, m=tid)
                d_np += 1.0f; d_cp += (lse - sc.y);
                float tx = (s_bcx[tid] - pr.x) * 10.0f / pr.z;
                float ty = (s_bcy[tid] - pr.y) * 10.0f / pr.w;
                float tw = __logf(s_bw[tid] / pr.z) * 5.0f;
                float th = __logf(s_bh[tid] / pr.w) * 5.0f;
                d_l1 += fabsf(pl.x - tx) + fabsf(pl.y - ty) + fabsf(pl.z - tw) + fabsf(pl.w - th);
                s_fv[tid] = 0.0f;                          // forced positive -> ce 0
            } else {
                s_fv[tid] = fmaxf(lse - sc.x, 0.0f);       // forced but label 0 -> negative ce
            }
            s_fp[tid] = p;
        }
    }
    if (tid < 64) {
#pragma unroll
        for (int off = 32; off; off >>= 1) {
            d_np += __shfl_down(d_np, off);
            d_l1 += __shfl_down(d_l1, off);
            d_cp += __shfl_down(d_cp, off);
        }
        if (tid == 0) {
            float np = s_sum[0] + d_np;
            rstats[(size_t)row * 8 + 0] = np;
            rstats[(size_t)row * 8 + 1] = s_sum[1] + d_l1;
            rstats[(size_t)row * 8 + 2] = s_sum[2] + d_cp;
            int K = NPR * (int)(np + 0.5f);
            s_K = (K > 0) ? (unsigned)K : 0u;
            s_prefix = 0u;
            s_Kr = (K > 0) ? (unsigned)K : 0u;
        }
    }
    __syncthreads();

    // compute ce_neg bit-patterns into registers, apply forced-prior fixes
    const float2* sc2 = (const float2*)(scores + (size_t)row * PP * 2);
    const unsigned char* pk = pk8 + (size_t)row * PP;
    unsigned int uv[EPT];
#pragma unroll
    for (int k = 0; k < EPT; k++) {
        int p = tid + k * CBLK;
        if (p < PP) {
            unsigned int u8 = pk[p];
            float2 sc = sc2[p];
            float ce = (u8 & 16u) ? 0.0f : fmaxf(lse2(sc.x, sc.y) - sc.x, 0.0f);
            uv[k] = __float_as_uint(ce);
        } else uv[k] = 0u;
    }
    for (int t = 0; t < MM; t++) {
        int fp = s_fp[t];
        if (fp >= 0) {
            unsigned int fb = __float_as_uint(s_fv[t]);
#pragma unroll
            for (int k = 0; k < EPT; k++) if (tid + k * CBLK == fp) uv[k] = fb;
        }
    }

    // 4-pass 256-bin histogram radix select for the K-th largest bit pattern
    const unsigned int K = s_K;
    unsigned int T = 0u;
    if (K > 0u && K < PP) {
        for (int pass = 0; pass < 4; pass++) {
            const int shift = 24 - 8 * pass;
            if (tid < 256) s_hist[tid] = 0u;
            __syncthreads();
            const unsigned int pref   = s_prefix;
            const unsigned int maskhi = (pass == 0) ? 0u : (0xffffffffu << (shift + 8));
#pragma unroll
            for (int k = 0; k < EPT; k++) {
                unsigned int u = uv[k];
                if ((u & maskhi) == pref) atomicAdd(&s_hist[(u >> shift) & 255u], 1u);
            }
            __syncthreads();
            if (wav == 0) {
                unsigned int Kr = s_Kr;
                unsigned int h0 = s_hist[lane * 4 + 0];
                unsigned int h1 = s_hist[lane * 4 + 1];
                unsigned int h2 = s_hist[lane * 4 + 2];
                unsigned int h3 = s_hist[lane * 4 + 3];
                unsigned int c3 = h3;
                unsigned int c2 = h3 + h2;
                unsigned int c1 = c2 + h1;
                unsigned int c0 = c1 + h0;
                unsigned int suf = c0;
#pragma unroll
                for (int off = 1; off < 64; off <<= 1) {
                    unsigned int o = __shfl_down(suf, off);
                    if (lane + off < 64) suf += o;
                }
                unsigned int above = suf - c0;
                int cand = -1;
                unsigned int G = 0;
                if      (c3 + above >= Kr) { cand = lane * 4 + 3; G = above + c3 - h3; }
                else if (c2 + above >= Kr) { cand = lane * 4 + 2; G = above + c2 - h2; }
                else if (c1 + above >= Kr) { cand = lane * 4 + 1; G = above + c1 - h1; }
                else if (c0 + above >= Kr) { cand = lane * 4 + 0; G = above + c0 - h0; }
                int best = cand;
#pragma unroll
                for (int off = 32; off; off >>= 1) best = max(best, __shfl_down(best, off));
                best = __shfl(best, 0);
                if (cand == best && cand >= 0) {
                    s_Kr = Kr - G;
                    s_prefix = pref | ((unsigned int)best << shift);
                }
            }
            __syncthreads();
        }
        T = s_prefix;
    }

    // sum strictly greater than pivot + ties * pivot
    float sgt = 0.0f; int cgt = 0;
    if (K > 0u) {
#pragma unroll
        for (int k = 0; k < EPT; k++) {
            unsigned int u = uv[k];
            if (u > T) { sgt += __uint_as_float(u); cgt++; }
        }
    }
#pragma unroll
    for (int off = 32; off; off >>= 1) {
        sgt += __shfl_down(sgt, off);
        cgt += __shfl_down(cgt, off);
    }
    if (lane == 0) { s_redf[wav] = sgt; s_redi[wav] = cgt; }
    __syncthreads();
    if (tid == 0) {
        float s = 0; int cnt = 0;
        for (int w = 0; w < 16; w++) { s += s_redf[w]; cnt += s_redi[w]; }
        float chard = (K > 0u) ? (s + (float)(int)(K - (unsigned)cnt) * __uint_as_float(T)) : 0.0f;
        rstats[(size_t)row * 8 + 4] = chard;
    }
}

// ---------------- Kernel C: final cross-row reduction ----------------
__global__ void mbox_finalize(const float* __restrict__ rstats, float* __restrict__ out) {
    int c = threadIdx.x;
    float loss = 0.0f;
    if (c < CC) {
        float np = 0, l1 = 0, cp = 0, ch = 0;
        for (int n = 0; n < NN; n++) {
            const float* s = rstats + ((size_t)(n * CC + c)) * 8;
            np += s[0]; l1 += s[1]; cp += s[2]; ch += s[4];
        }
        float loc = l1 / fmaxf(np * 4.0f, 1.0f);
        float val = (np > 0.0f) ? (cp + ch + loc) / fmaxf(np, 1.0f) : 0.0f;
        loss = val / (float)CC;
    }
#pragma unroll
    for (int off = 32; off; off >>= 1) loss += __shfl_down(loss, off);
    if (threadIdx.x == 0) out[0] = loss;
}

extern "C" void kernel_launch(void* const* d_in, const int* in_sizes, int n_in,
                              void* d_out, int out_size, void* d_ws, size_t ws_size,
                              hipStream_t stream) {
    const float* locs   = (const float*)d_in[0];
    const float* scores = (const float*)d_in[1];
    const float* boxes  = (const float*)d_in[2];
    const int*   labels = (const int*)d_in[3];
    const float* priors = (const float*)d_in[4];
    float* out = (float*)d_out;

    char* ws = (char*)d_ws;
    unsigned char* pk8           = (unsigned char*)ws;                  // 1,397,120 B
    unsigned long long* partials = (unsigned long long*)(ws + 1397120); //   245,760 B
    float* cstats                = (float*)(ws + 1642880);              //    23,040 B
    float* rstats                = (float*)(ws + 1665920);              //     5,120 B

    mbox_p1<<<ROWS * SPLIT, ABLK, 0, stream>>>(locs, scores, boxes, labels, priors,
                                               pk8, partials, cstats);
    mbox_sel<<<ROWS, CBLK, 0, stream>>>(locs, scores, boxes, labels, priors,
                                        pk8, partials, cstats, rstats);
    mbox_finalize<<<1, 64, 0, stream>>>(rstats, out);
}